// Round 2
// baseline (650.019 us; speedup 1.0000x reference)
//
#include <hip/hip_runtime.h>
#include <math.h>

#define N 8192
#define D 64
#define E_K 262144
#define E_HK 262144
#define NEDGE (E_K + E_HK)      // 524288
#define NENT  (2 * NEDGE)       // 1048576 CSR entries

constexpr float INV_KAPPA = 0.5f;  // 1/KAPPA_H == 1/KAPPA_K == 0.5

__device__ inline float fast_tanh(float x) {
  x = fminf(15.f, fmaxf(-15.f, x));
  float e = __expf(2.f * x);
  return (e - 1.f) * __builtin_amdgcn_rcpf(e + 1.f);
}

__device__ inline float wave_reduce(float v) {
  #pragma unroll
  for (int off = 32; off > 0; off >>= 1) v += __shfl_xor(v, off);
  return v;
}

// -------- kernel 1: Knorm, g=tanh(H), skew-omega, zero counts --------
__global__ __launch_bounds__(256) void prep_kernel(
    const float* __restrict__ state_K, const float* __restrict__ state_H,
    const float* __restrict__ omega,
    float* __restrict__ Knorm, float* __restrict__ g, float* __restrict__ Om,
    int* __restrict__ counts) {
  int tid  = blockIdx.x * blockDim.x + threadIdx.x;
  int wave = tid >> 6;
  int lane = threadIdx.x & 63;
  if (wave < N) {
    float v = state_K[wave * D + lane];
    float ss = wave_reduce(v * v);
    Knorm[wave * D + lane] = v * __builtin_amdgcn_rcpf(sqrtf(ss));
  }
  if (tid < N) g[tid] = fast_tanh(state_H[tid]);
  if (tid < D * D) {
    int a = tid >> 6, b = tid & 63;
    Om[tid] = 0.5f * (omega[a * D + b] - omega[b * D + a]);
  }
  if (tid < N) counts[tid] = 0;
}

// -------- kernel 2: degree count (1 thread per edge) --------
__global__ __launch_bounds__(256) void count_kernel(
    const int* __restrict__ ind_HK, const int* __restrict__ ind_K,
    int* __restrict__ counts) {
  int t = blockIdx.x * blockDim.x + threadIdx.x;
  if (t < E_HK) {
    atomicAdd(&counts[ind_HK[2 * t]], 1);
    atomicAdd(&counts[ind_HK[2 * t + 1]], 1);
  } else if (t < NEDGE) {
    int e = t - E_HK;
    atomicAdd(&counts[ind_K[2 * e]], 1);
    atomicAdd(&counts[ind_K[2 * e + 1]], 1);
  }
}

// -------- kernel 3: exclusive prefix scan over 8192 counts (1 block) --------
__global__ __launch_bounds__(1024) void scan_kernel(
    const int* __restrict__ counts, int* __restrict__ rowstart,
    int* __restrict__ cursor) {
  __shared__ int part[1024];
  int tid = threadIdx.x;
  int base = tid * 8;
  int local[8];
  int s = 0;
  #pragma unroll
  for (int k = 0; k < 8; ++k) { local[k] = s; s += counts[base + k]; }
  part[tid] = s;
  __syncthreads();
  for (int off = 1; off < 1024; off <<= 1) {
    int v = (tid >= off) ? part[tid - off] : 0;
    __syncthreads();
    if (tid >= off) part[tid] += v;
    __syncthreads();
  }
  int prev = (tid == 0) ? 0 : part[tid - 1];
  #pragma unroll
  for (int k = 0; k < 8; ++k) {
    int v = prev + local[k];
    rowstart[base + k] = v;
    cursor[base + k] = v;
  }
  if (tid == 1023) rowstart[N] = part[1023];
}

// -------- kernel 4: per-edge coeff + CSR fill (1 wave per edge) --------
// entry.x = other | (HK ? 1<<31 : 0); entry.y = dot (HK) or dE/ds (K)
__global__ __launch_bounds__(256) void scatter_kernel(
    const int* __restrict__ ind_HK, const int* __restrict__ ind_K,
    const float* __restrict__ Knorm,
    const float* __restrict__ w1, const float* __restrict__ b1,
    const float* __restrict__ w2,
    int* __restrict__ cursor, int2* __restrict__ entries) {
  int wid  = (blockIdx.x * blockDim.x + threadIdx.x) >> 6;
  int lane = threadIdx.x & 63;
  if (wid >= NEDGE) return;
  int i, j, hkbit;
  if (wid < E_HK) {
    i = ind_HK[2 * wid]; j = ind_HK[2 * wid + 1]; hkbit = (int)0x80000000;
  } else {
    int e = wid - E_HK;
    i = ind_K[2 * e]; j = ind_K[2 * e + 1]; hkbit = 0;
  }
  float ki = Knorm[i * D + lane];
  float kj = Knorm[j * D + lane];
  float dot = wave_reduce(ki * kj);
  float val;
  if (hkbit) {
    val = dot;
  } else {
    val = wave_reduce(fast_tanh(dot * w1[lane] + b1[lane]) * w2[lane]);
  }
  if (lane == 0) {
    int s0 = atomicAdd(&cursor[i], 1);
    entries[s0] = make_int2(j | hkbit, __float_as_int(val));
    int s1 = atomicAdd(&cursor[j], 1);
    entries[s1] = make_int2(i | hkbit, __float_as_int(val));
  }
}

// -------- kernel 5: f_H = -state_H + W_H @ g --------
__global__ __launch_bounds__(256) void matvec_kernel(
    const float* __restrict__ W_H, const float* __restrict__ g,
    const float* __restrict__ state_H, float* __restrict__ f_H) {
  int row = blockIdx.x;
  const float4* Wrow = reinterpret_cast<const float4*>(W_H + (size_t)row * N);
  const float4* g4   = reinterpret_cast<const float4*>(g);
  float acc = 0.0f;
  #pragma unroll
  for (int c = threadIdx.x; c < N / 4; c += 256) {
    float4 w = Wrow[c];
    float4 gg = g4[c];
    acc += w.x * gg.x + w.y * gg.y + w.z * gg.z + w.w * gg.w;
  }
  acc = wave_reduce(acc);
  __shared__ float sbuf[4];
  if ((threadIdx.x & 63) == 0) sbuf[threadIdx.x >> 6] = acc;
  __syncthreads();
  if (threadIdx.x == 0)
    f_H[row] = -state_H[row] + sbuf[0] + sbuf[1] + sbuf[2] + sbuf[3];
}

// -------- kernel 6: CSR gather + finalize (1 block = 4 waves per row) -----
__global__ __launch_bounds__(256) void gather_kernel(
    const float* __restrict__ Knorm, const float* __restrict__ g,
    const float* __restrict__ Om,
    const int* __restrict__ rowstart, const int2* __restrict__ entries,
    float* __restrict__ f_H, float* __restrict__ f_K) {
  int row  = blockIdx.x;
  int lane = threadIdx.x & 63;
  int wv   = threadIdx.x >> 6;
  float kr = Knorm[row * D + lane];
  float gr = g[row];
  int start = rowstart[row], end = rowstart[row + 1];
  float acc = 0.f;   // A[row][lane]
  float sumH = 0.f;  // f_H edge contribution (lane-replicated)
  for (int e = start + wv; e < end; e += 4) {
    int2 ent = entries[e];
    int other = ent.x & 0x7FFFFFFF;
    float val = __int_as_float(ent.y);
    float ko = Knorm[other * D + lane];
    float cK;
    if (ent.x < 0) {           // HK edge: val = Gram dot
      float go = g[other];
      cK = -gr * go * INV_KAPPA;
      sumH += val * go * INV_KAPPA;
    } else {                   // K edge: val = dE/ds
      cK = val;
    }
    acc += cK * ko;
  }
  __shared__ float sAcc[4][D];
  __shared__ float sH[4];
  sAcc[wv][lane] = acc;
  if (lane == 0) sH[wv] = sumH;
  __syncthreads();
  if (wv == 0) {
    float tot = sAcc[0][lane] + sAcc[1][lane] + sAcc[2][lane] + sAcc[3][lane];
    float rd = wave_reduce(kr * tot);
    float ko = 0.f;
    #pragma unroll
    for (int d = 0; d < D; ++d)
      ko += __shfl(kr, d) * Om[d * D + lane];
    f_K[row * D + lane] = -tot + kr * rd + ko;
    if (lane == 0) f_H[row] += sH[0] + sH[1] + sH[2] + sH[3];
  }
}

extern "C" void kernel_launch(void* const* d_in, const int* in_sizes, int n_in,
                              void* d_out, int out_size, void* d_ws, size_t ws_size,
                              hipStream_t stream) {
  const float* state_H = (const float*)d_in[0];
  const float* state_K = (const float*)d_in[1];
  const float* W_H     = (const float*)d_in[2];
  const float* omega   = (const float*)d_in[3];
  const float* w1      = (const float*)d_in[4];
  const float* b1      = (const float*)d_in[5];
  const float* w2      = (const float*)d_in[6];
  const int*   ind_K   = (const int*)d_in[7];
  const int*   ind_HK  = (const int*)d_in[8];

  float* f_H = (float*)d_out;       // N
  float* f_K = (float*)d_out + N;   // N*D

  char* ws = (char*)d_ws;
  int2*  entries  = (int2*)ws;                 ws += (size_t)NENT * sizeof(int2);   // 8 MB
  float* Knorm    = (float*)ws;                ws += (size_t)N * D * sizeof(float); // 2 MB
  float* g        = (float*)ws;                ws += N * sizeof(float);
  float* Om       = (float*)ws;                ws += D * D * sizeof(float);
  int*   counts   = (int*)ws;                  ws += N * sizeof(int);
  int*   rowstart = (int*)ws;                  ws += (N + 1) * sizeof(int);
  int*   cursor   = (int*)ws;

  prep_kernel<<<(N * 64) / 256, 256, 0, stream>>>(state_K, state_H, omega,
                                                  Knorm, g, Om, counts);
  count_kernel<<<NEDGE / 256, 256, 0, stream>>>(ind_HK, ind_K, counts);
  scan_kernel<<<1, 1024, 0, stream>>>(counts, rowstart, cursor);
  scatter_kernel<<<(NEDGE * 64) / 256, 256, 0, stream>>>(
      ind_HK, ind_K, Knorm, w1, b1, w2, cursor, entries);
  matvec_kernel<<<N, 256, 0, stream>>>(W_H, g, state_H, f_H);
  gather_kernel<<<N, 256, 0, stream>>>(Knorm, g, Om, rowstart, entries, f_H, f_K);
}

// Round 3
// 544.241 us; speedup vs baseline: 1.1944x; 1.1944x over previous
//
#include <hip/hip_runtime.h>
#include <math.h>

#define N 8192
#define D 64
#define E_K 262144
#define E_HK 262144
#define NEDGE (E_K + E_HK)   // 524288
#define CAP 256              // slots per row; mean degree 128, sigma ~11 -> +11 sigma

constexpr float INV_KAPPA = 0.5f;  // 1/KAPPA_H == 1/KAPPA_K == 0.5

__device__ inline float fast_tanh(float x) {
  x = fminf(15.f, fmaxf(-15.f, x));
  float e = __expf(2.f * x);
  return (e - 1.f) * __builtin_amdgcn_rcpf(e + 1.f);
}

__device__ inline float wave_reduce(float v) {
  #pragma unroll
  for (int off = 32; off > 0; off >>= 1) v += __shfl_xor(v, off);
  return v;
}

// -------- kernel 1: Knorm rows, g = tanh(H), skew-omega --------
__global__ __launch_bounds__(256) void prep_kernel(
    const float* __restrict__ state_K, const float* __restrict__ state_H,
    const float* __restrict__ omega,
    float* __restrict__ Knorm, float* __restrict__ g, float* __restrict__ Om) {
  int tid  = blockIdx.x * blockDim.x + threadIdx.x;
  int wave = tid >> 6;
  int lane = threadIdx.x & 63;
  if (wave < N) {
    float v = state_K[wave * D + lane];
    float ss = wave_reduce(v * v);
    Knorm[wave * D + lane] = v * __builtin_amdgcn_rcpf(sqrtf(ss));
  }
  if (tid < N) g[tid] = fast_tanh(state_H[tid]);
  if (tid < D * D) {
    int a = tid >> 6, b = tid & 63;
    Om[tid] = 0.5f * (omega[a * D + b] - omega[b * D + a]);
  }
}

// -------- kernel 2: index push into fixed-CAP row buckets (1 thr/edge) ----
// entry = other | (HK ? 1<<31 : 0)
__global__ __launch_bounds__(256) void scatter_kernel(
    const int* __restrict__ ind_HK, const int* __restrict__ ind_K,
    int* __restrict__ cursor, int* __restrict__ entries) {
  int t = blockIdx.x * blockDim.x + threadIdx.x;
  if (t >= NEDGE) return;
  int i, j, bit;
  if (t < E_HK) {
    int2 e = ((const int2*)ind_HK)[t];
    i = e.x; j = e.y; bit = (int)0x80000000;
  } else {
    int2 e = ((const int2*)ind_K)[t - E_HK];
    i = e.x; j = e.y; bit = 0;
  }
  int s0 = atomicAdd(&cursor[i], 1);
  if (s0 < CAP) entries[i * CAP + s0] = j | bit;
  int s1 = atomicAdd(&cursor[j], 1);
  if (s1 < CAP) entries[j * CAP + s1] = i | bit;
}

// -------- kernel 3: f_H = -state_H + W_H @ g (one block per row) ----------
__global__ __launch_bounds__(256) void matvec_kernel(
    const float* __restrict__ W_H, const float* __restrict__ g,
    const float* __restrict__ state_H, float* __restrict__ f_H) {
  int row = blockIdx.x;
  const float4* Wrow = reinterpret_cast<const float4*>(W_H + (size_t)row * N);
  const float4* g4   = reinterpret_cast<const float4*>(g);
  float acc = 0.0f;
  #pragma unroll
  for (int c = threadIdx.x; c < N / 4; c += 256) {
    float4 w = Wrow[c];
    float4 gg = g4[c];
    acc += w.x * gg.x + w.y * gg.y + w.z * gg.z + w.w * gg.w;
  }
  acc = wave_reduce(acc);
  __shared__ float sbuf[4];
  if ((threadIdx.x & 63) == 0) sbuf[threadIdx.x >> 6] = acc;
  __syncthreads();
  if (threadIdx.x == 0)
    f_H[row] = -state_H[row] + sbuf[0] + sbuf[1] + sbuf[2] + sbuf[3];
}

// -------- kernel 4: per-row gather, recompute edge scalars, finalize ------
__global__ __launch_bounds__(256) void gather_kernel(
    const float* __restrict__ Knorm, const float* __restrict__ g,
    const float* __restrict__ Om, const float* __restrict__ w1,
    const float* __restrict__ b1, const float* __restrict__ w2,
    const int* __restrict__ cursor, const int* __restrict__ entries,
    float* __restrict__ f_H, float* __restrict__ f_K) {
  __shared__ int   sh_ent[CAP];
  __shared__ float sAcc[4][D];
  __shared__ float sH[4];
  int row  = blockIdx.x;
  int lane = threadIdx.x & 63;
  int wv   = threadIdx.x >> 6;
  int len  = min(cursor[row], CAP);
  for (int e = threadIdx.x; e < len; e += 256)
    sh_ent[e] = entries[row * CAP + e];
  float kr  = Knorm[row * D + lane];
  float gr  = g[row];
  float w1l = w1[lane], b1l = b1[lane], w2l = w2[lane];
  __syncthreads();
  float acc  = 0.f;   // A[row][lane]
  float sumH = 0.f;   // f_H edge contribution (lane-replicated)
  for (int e = wv; e < len; e += 4) {
    int ent   = sh_ent[e];
    int other = ent & 0x7FFFFFFF;
    float ko  = Knorm[other * D + lane];
    float dot = wave_reduce(kr * ko);
    if (ent < 0) {              // HK edge
      float go = g[other];
      acc  += (-gr * go * INV_KAPPA) * ko;
      sumH += dot * go * INV_KAPPA;
    } else {                    // K edge: dE/ds via 64-wide MLP in-lane
      float de = wave_reduce(fast_tanh(dot * w1l + b1l) * w2l);
      acc += de * ko;
    }
  }
  sAcc[wv][lane] = acc;
  if (lane == 0) sH[wv] = sumH;
  __syncthreads();
  if (wv == 0) {
    float tot = sAcc[0][lane] + sAcc[1][lane] + sAcc[2][lane] + sAcc[3][lane];
    float rd = wave_reduce(kr * tot);
    float ko = 0.f;
    #pragma unroll
    for (int d = 0; d < D; ++d)
      ko += __shfl(kr, d) * Om[d * D + lane];
    f_K[row * D + lane] = -tot + kr * rd + ko;
    if (lane == 0) f_H[row] += sH[0] + sH[1] + sH[2] + sH[3];
  }
}

extern "C" void kernel_launch(void* const* d_in, const int* in_sizes, int n_in,
                              void* d_out, int out_size, void* d_ws, size_t ws_size,
                              hipStream_t stream) {
  const float* state_H = (const float*)d_in[0];
  const float* state_K = (const float*)d_in[1];
  const float* W_H     = (const float*)d_in[2];
  const float* omega   = (const float*)d_in[3];
  const float* w1      = (const float*)d_in[4];
  const float* b1      = (const float*)d_in[5];
  const float* w2      = (const float*)d_in[6];
  const int*   ind_K   = (const int*)d_in[7];
  const int*   ind_HK  = (const int*)d_in[8];

  float* f_H = (float*)d_out;       // N
  float* f_K = (float*)d_out + N;   // N*D

  char* ws = (char*)d_ws;
  int*   entries = (int*)ws;                ws += (size_t)N * CAP * sizeof(int);   // 8 MB
  float* Knorm   = (float*)ws;              ws += (size_t)N * D * sizeof(float);   // 2 MB
  float* g       = (float*)ws;              ws += N * sizeof(float);
  float* Om      = (float*)ws;              ws += D * D * sizeof(float);
  int*   cursor  = (int*)ws;

  hipMemsetAsync(cursor, 0, N * sizeof(int), stream);
  prep_kernel<<<(N * 64) / 256, 256, 0, stream>>>(state_K, state_H, omega,
                                                  Knorm, g, Om);
  scatter_kernel<<<NEDGE / 256, 256, 0, stream>>>(ind_HK, ind_K, cursor, entries);
  matvec_kernel<<<N, 256, 0, stream>>>(W_H, g, state_H, f_H);
  gather_kernel<<<N, 256, 0, stream>>>(Knorm, g, Om, w1, b1, w2,
                                       cursor, entries, f_H, f_K);
}

// Round 5
// 499.231 us; speedup vs baseline: 1.3020x; 1.0902x over previous
//
#include <hip/hip_runtime.h>
#include <math.h>

#define N 8192
#define D 64
#define E_K 262144
#define E_HK 262144
#define NEDGE (E_K + E_HK)   // 524288
#define CAP 256              // slots/row; degree mean 128, sigma ~11 -> safe

constexpr float INV_KAPPA = 0.5f;  // 1/KAPPA_H == 1/KAPPA_K

__device__ inline float fast_tanh(float x) {
  x = fminf(15.f, fmaxf(-15.f, x));
  float e = __expf(2.f * x);
  return (e - 1.f) * __builtin_amdgcn_rcpf(e + 1.f);
}

__device__ inline float wave_reduce(float v) {
  #pragma unroll
  for (int off = 32; off > 0; off >>= 1) v += __shfl_xor(v, off);
  return v;
}

// ---- kernel 1: fused prep (Knorm, g, Om) + edge index scatter ----
// blocks [0,2048): 1 thread/edge index push; blocks [2048,4096): 4 rows/block
// normalize + g; block 4096: skew-omega.
__global__ __launch_bounds__(256) void prep_scatter_kernel(
    const float* __restrict__ state_K, const float* __restrict__ state_H,
    const float* __restrict__ omega,
    const int* __restrict__ ind_HK, const int* __restrict__ ind_K,
    float* __restrict__ Knorm, float* __restrict__ g, float* __restrict__ Om,
    int* __restrict__ cursor, int* __restrict__ entries) {
  int b = blockIdx.x;
  if (b < 2048) {                      // ---- scatter: one thread per edge
    int t = b * 256 + threadIdx.x;
    int i, j, bit;
    if (t < E_HK) {
      int2 e = ((const int2*)ind_HK)[t];
      i = e.x; j = e.y; bit = (int)0x80000000;
    } else {
      int2 e = ((const int2*)ind_K)[t - E_HK];
      i = e.x; j = e.y; bit = 0;
    }
    int s0 = atomicAdd(&cursor[i], 1);
    if (s0 < CAP) entries[i * CAP + s0] = j | bit;
    int s1 = atomicAdd(&cursor[j], 1);
    if (s1 < CAP) entries[j * CAP + s1] = i | bit;
  } else if (b < 4096) {               // ---- prep: 4 rows per block
    int lane = threadIdx.x & 63;
    int row  = (b - 2048) * 4 + (threadIdx.x >> 6);
    float v  = state_K[row * D + lane];
    float ss = wave_reduce(v * v);
    Knorm[row * D + lane] = v * __builtin_amdgcn_rcpf(sqrtf(ss));
    if (lane == 0) g[row] = fast_tanh(state_H[row]);
  } else {                             // ---- skew-omega (one block)
    for (int t = threadIdx.x; t < D * D; t += 256) {
      int a = t >> 6, c = t & 63;
      Om[t] = 0.5f * (omega[a * D + c] - omega[c * D + a]);
    }
  }
}

// ---- kernel 2: mega — W_H matvec + edge gather + finalize, block per row --
__global__ __launch_bounds__(256) void mega_kernel(
    const float* __restrict__ W_H, const float* __restrict__ state_H,
    const float* __restrict__ Knorm, const float* __restrict__ g,
    const float* __restrict__ Om, const float* __restrict__ w1,
    const float* __restrict__ b1, const float* __restrict__ w2,
    const int* __restrict__ cursor, const int* __restrict__ entries,
    float* __restrict__ f_H, float* __restrict__ f_K) {
  int row  = blockIdx.x;
  int lane = threadIdx.x & 63;
  int wv   = threadIdx.x >> 6;

  // stage the 32 KB W row early; gather runs under these HBM loads
  const float4* Wrow = reinterpret_cast<const float4*>(W_H + (size_t)row * N);
  float4 wreg[8];
  #pragma unroll
  for (int k = 0; k < 8; ++k) wreg[k] = Wrow[threadIdx.x + k * 256];

  float kr  = Knorm[row * D + lane];
  float gr  = g[row];
  float w1l = w1[lane], b1l = b1[lane], w2l = w2[lane];

  __shared__ int sh_ent[CAP];
  int len = min(cursor[row], CAP);
  for (int e = threadIdx.x; e < len; e += 256)
    sh_ent[e] = entries[row * CAP + e];
  __syncthreads();

  float acc  = 0.f;  // A[row][lane]
  float accH = 0.f;  // Σ_HK g[other]*K[other][lane]  (dot folded out)
  for (int e = wv; e < len; e += 4) {
    int ent   = sh_ent[e];
    int other = ent & 0x7FFFFFFF;
    float ko  = Knorm[other * D + lane];
    if (ent < 0) {                    // HK edge: no per-entry reduce needed
      float go = g[other];
      acc  += (-gr * go * INV_KAPPA) * ko;
      accH += go * ko;
    } else {                          // K edge: dot -> 64-wide MLP -> de
      float dot = wave_reduce(kr * ko);
      float de  = wave_reduce(fast_tanh(dot * w1l + b1l) * w2l);
      acc += de * ko;
    }
  }

  // consume staged W row against g
  const float4* g4 = reinterpret_cast<const float4*>(g);
  float mv = 0.f;
  #pragma unroll
  for (int k = 0; k < 8; ++k) {
    float4 gg = g4[threadIdx.x + k * 256];
    mv += wreg[k].x * gg.x + wreg[k].y * gg.y +
          wreg[k].z * gg.z + wreg[k].w * gg.w;
  }
  mv = wave_reduce(mv);

  __shared__ float sAcc[4][D];
  __shared__ float sAccH[4][D];
  __shared__ float sMv[4];
  sAcc[wv][lane]  = acc;
  sAccH[wv][lane] = accH;
  if (lane == 0) sMv[wv] = mv;
  __syncthreads();

  if (wv == 0) {
    float tot  = sAcc[0][lane] + sAcc[1][lane] + sAcc[2][lane] + sAcc[3][lane];
    float totH = sAccH[0][lane] + sAccH[1][lane] + sAccH[2][lane] + sAccH[3][lane];
    float rd = wave_reduce(kr * tot);          // rowdot(K, A)
    float sh = wave_reduce(kr * totH);         // Σ_e dot_e * g[other_e]
    float krot = 0.f;
    #pragma unroll
    for (int d = 0; d < D; ++d)
      krot += __shfl(kr, d) * Om[d * D + lane];
    f_K[row * D + lane] = -tot + kr * rd + krot;
    if (lane == 0)
      f_H[row] = -state_H[row] + sMv[0] + sMv[1] + sMv[2] + sMv[3]
                 + sh * INV_KAPPA;
  }
}

extern "C" void kernel_launch(void* const* d_in, const int* in_sizes, int n_in,
                              void* d_out, int out_size, void* d_ws, size_t ws_size,
                              hipStream_t stream) {
  const float* state_H = (const float*)d_in[0];
  const float* state_K = (const float*)d_in[1];
  const float* W_H     = (const float*)d_in[2];
  const float* omega   = (const float*)d_in[3];
  const float* w1      = (const float*)d_in[4];
  const float* b1      = (const float*)d_in[5];
  const float* w2      = (const float*)d_in[6];
  const int*   ind_K   = (const int*)d_in[7];
  const int*   ind_HK  = (const int*)d_in[8];

  float* f_H = (float*)d_out;       // N
  float* f_K = (float*)d_out + N;   // N*D

  char* ws = (char*)d_ws;
  int*   entries = (int*)ws;               ws += (size_t)N * CAP * sizeof(int);  // 8 MB
  float* Knorm   = (float*)ws;             ws += (size_t)N * D * sizeof(float);  // 2 MB
  float* g       = (float*)ws;             ws += N * sizeof(float);
  float* Om      = (float*)ws;             ws += D * D * sizeof(float);
  int*   cursor  = (int*)ws;

  hipMemsetAsync(cursor, 0, N * sizeof(int), stream);
  prep_scatter_kernel<<<4097, 256, 0, stream>>>(
      state_K, state_H, omega, ind_HK, ind_K, Knorm, g, Om, cursor, entries);
  mega_kernel<<<N, 256, 0, stream>>>(W_H, state_H, Knorm, g, Om, w1, b1, w2,
                                     cursor, entries, f_H, f_K);
}